// Round 1
// baseline (671.886 us; speedup 1.0000x reference)
//
#include <hip/hip_runtime.h>

typedef __attribute__((ext_vector_type(8))) short short8;
typedef __attribute__((ext_vector_type(4))) float floatx4;
typedef __attribute__((ext_vector_type(4))) unsigned short ushort4v;
typedef unsigned short u16;

#define DEV __device__ __forceinline__

DEV u16 f2bf(float f) {
  unsigned int u = __float_as_uint(f);
  u += 0x7fffu + ((u >> 16) & 1u);
  return (u16)(u >> 16);
}
DEV float bf2f(u16 h) { return __uint_as_float(((unsigned int)h) << 16); }
DEV float silu_f(float x) { return x / (1.f + __expf(-x)); }
DEV floatx4 fzero() { floatx4 z = {0.f, 0.f, 0.f, 0.f}; return z; }
DEV floatx4 mfma16(short8 a, short8 b, floatx4 c) {
  return __builtin_amdgcn_mfma_f32_16x16x32_bf16(a, b, c, 0, 0, 0);
}
DEV void gll16(const void* g, void* l) {
  __builtin_amdgcn_global_load_lds((__attribute__((address_space(1))) void*)g,
                                   (__attribute__((address_space(3))) void*)l,
                                   16, 0, 0);
}

// ---------------- cast x (f32 -> bf16) ----------------
__global__ __launch_bounds__(256) void cast_x_kernel(const float* __restrict__ x,
                                                     u16* __restrict__ xb, int n4) {
  int i = blockIdx.x * 256 + threadIdx.x;
  if (i >= n4) return;
  float4 v = ((const float4*)x)[i];
  ushort4v o;
  o[0] = f2bf(v.x); o[1] = f2bf(v.y); o[2] = f2bf(v.z); o[3] = f2bf(v.w);
  *(ushort4v*)&xb[(size_t)i * 4] = o;
}

// ---------------- transpose+cast: W[K][N] f32 -> WT[N][K] bf16 ----------------
__global__ __launch_bounds__(256) void transpose_cast_kernel(const float* __restrict__ W,
                                                             u16* __restrict__ WT,
                                                             int K, int N) {
  __shared__ u16 tile[32][36];
  int n0 = blockIdx.x * 32, k0 = blockIdx.y * 32;
  int t = threadIdx.x;
  int r = t >> 3, cs = (t & 7) * 4;
  float4 v = *(const float4*)&W[(size_t)(k0 + r) * N + n0 + cs];
  tile[r][cs + 0] = f2bf(v.x);
  tile[r][cs + 1] = f2bf(v.y);
  tile[r][cs + 2] = f2bf(v.z);
  tile[r][cs + 3] = f2bf(v.w);
  __syncthreads();
  ushort4v o;
  o[0] = tile[cs + 0][r];
  o[1] = tile[cs + 1][r];
  o[2] = tile[cs + 2][r];
  o[3] = tile[cs + 3][r];
  *(ushort4v*)&WT[(size_t)(n0 + r) * K + k0 + cs] = o;
}

// ---------------- transposed bf16 store helper (wave 64x64 tile in tr[64][72]) ----
DEV void wave_transposed_store(u16* __restrict__ Ct, long chunk_stride,
                               const u16* trw, int chunk, int cbase, int nbase,
                               int lane) {
#pragma unroll
  for (int it = 0; it < 8; ++it) {
    int e_l = it * 8 + (lane >> 3);
    int c_off = (lane & 7) * 8;
    short8 val = *(const short8*)&trw[e_l * 72 + c_off];
    *(short8*)&Ct[(size_t)chunk * chunk_stride + (size_t)(nbase + e_l) * 256 + cbase +
                  c_off] = val;
  }
}

// ---------------- GEMM: C = A[M,K] * Bt[N,K]^T, bf16 MFMA, 128x128x32 ----------
// MODE 0: silu -> bf16 natural (gate)
// MODE 1: silu -> bf16 transposed per-chunk (vT)
// MODE 2: silu -> qq/qk/lq natural (affine) + lkT transposed (affine)
// MODE 3: +bias -> fp32 natural (final output)
template <int MODE>
__global__ __launch_bounds__(256) void gemm_bt(
    const u16* __restrict__ A, const u16* __restrict__ Bt, int M, int N, int K,
    const float* __restrict__ bias, u16* __restrict__ Cn, float* __restrict__ Cf,
    u16* __restrict__ Ct, long ct_stride, u16* __restrict__ Cn2, u16* __restrict__ Cn3,
    const float* __restrict__ gqq, const float* __restrict__ bqq,
    const float* __restrict__ gqk, const float* __restrict__ bqk,
    const float* __restrict__ glq, const float* __restrict__ blq,
    const float* __restrict__ glk, const float* __restrict__ blk) {
  __shared__ union {
    struct { u16 a[128 * 32]; u16 b[128 * 32]; } st;
    u16 tr[4 * 64 * 72];
  } sm;
  const int t = threadIdx.x;
  const int wave = t >> 6, lane = t & 63;
  const int l15 = lane & 15, l16 = lane >> 4;
  const int n0 = blockIdx.x * 128, m0 = blockIdx.y * 128;
  const int wm = (wave >> 1) * 64, wn = (wave & 1) * 64;

  floatx4 acc[4][4];
#pragma unroll
  for (int i = 0; i < 4; ++i)
#pragma unroll
    for (int j = 0; j < 4; ++j) acc[i][j] = fzero();

  const int c0 = t, c1 = 256 + t;
  const u16* pa0 = A + (size_t)(m0 + (c0 >> 2)) * K + (c0 & 3) * 8;
  const u16* pa1 = A + (size_t)(m0 + (c1 >> 2)) * K + (c1 & 3) * 8;
  const u16* pb0 = Bt + (size_t)(n0 + (c0 >> 2)) * K + (c0 & 3) * 8;
  const u16* pb1 = Bt + (size_t)(n0 + (c1 >> 2)) * K + (c1 & 3) * 8;

  for (int k0 = 0; k0 < K; k0 += 32) {
    __syncthreads();
    gll16(pa0 + k0, &sm.st.a[c0 * 8]);
    gll16(pa1 + k0, &sm.st.a[c1 * 8]);
    gll16(pb0 + k0, &sm.st.b[c0 * 8]);
    gll16(pb1 + k0, &sm.st.b[c1 * 8]);
    __syncthreads();
    short8 af[4], bfr[4];
#pragma unroll
    for (int mi = 0; mi < 4; ++mi)
      af[mi] = *(const short8*)&sm.st.a[(wm + mi * 16 + l15) * 32 + l16 * 8];
#pragma unroll
    for (int ni = 0; ni < 4; ++ni)
      bfr[ni] = *(const short8*)&sm.st.b[(wn + ni * 16 + l15) * 32 + l16 * 8];
#pragma unroll
    for (int mi = 0; mi < 4; ++mi)
#pragma unroll
      for (int ni = 0; ni < 4; ++ni)
        acc[mi][ni] = mfma16(af[mi], bfr[ni], acc[mi][ni]);
  }
  __syncthreads();

  if constexpr (MODE == 0) {
#pragma unroll
    for (int mi = 0; mi < 4; ++mi)
#pragma unroll
      for (int ni = 0; ni < 4; ++ni) {
        const int col = n0 + wn + ni * 16 + l15;
        const float bc = bias[col];
        const int row = m0 + wm + mi * 16 + l16 * 4;
#pragma unroll
        for (int r = 0; r < 4; ++r)
          Cn[(size_t)(row + r) * N + col] = f2bf(silu_f(acc[mi][ni][r] + bc));
      }
  } else if constexpr (MODE == 3) {
#pragma unroll
    for (int mi = 0; mi < 4; ++mi)
#pragma unroll
      for (int ni = 0; ni < 4; ++ni) {
        const int col = n0 + wn + ni * 16 + l15;
        const float bc = bias[col];
        const int row = m0 + wm + mi * 16 + l16 * 4;
#pragma unroll
        for (int r = 0; r < 4; ++r)
          Cf[(size_t)(row + r) * N + col] = acc[mi][ni][r] + bc;
      }
  } else if constexpr (MODE == 1) {
    u16* trw = &sm.tr[wave * 64 * 72];
#pragma unroll
    for (int mi = 0; mi < 4; ++mi)
#pragma unroll
      for (int ni = 0; ni < 4; ++ni) {
        const int col = n0 + wn + ni * 16 + l15;
        const float bc = bias[col];
        ushort4v p;
#pragma unroll
        for (int r = 0; r < 4; ++r) p[r] = f2bf(silu_f(acc[mi][ni][r] + bc));
        *(ushort4v*)&trw[(ni * 16 + l15) * 72 + mi * 16 + l16 * 4] = p;
      }
    wave_transposed_store(Ct, ct_stride, trw, (m0 + wm) >> 8, (m0 + wm) & 255,
                          n0 + wn, lane);
  } else {  // MODE 2
    u16* trw = &sm.tr[wave * 64 * 72];
#pragma unroll
    for (int mi = 0; mi < 4; ++mi)
#pragma unroll
      for (int ni = 0; ni < 4; ++ni) {
        const int col = wn + ni * 16 + l15;
        const float bc = bias[col];
        const float Gqq = gqq[col], Bqq = bqq[col];
        const float Gqk = gqk[col], Bqk = bqk[col];
        const float Glq = glq[col], Blq = blq[col];
        const float Glk = glk[col], Blk = blk[col];
        const int row = m0 + wm + mi * 16 + l16 * 4;
        ushort4v p;
#pragma unroll
        for (int r = 0; r < 4; ++r) {
          const float sv = silu_f(acc[mi][ni][r] + bc);
          const size_t ad = (size_t)(row + r) * N + col;
          Cn[ad] = f2bf(sv * Gqq + Bqq);
          Cn2[ad] = f2bf(sv * Gqk + Bqk);
          Cn3[ad] = f2bf(sv * Glq + Blq);
          p[r] = f2bf(sv * Glk + Blk);
        }
        *(ushort4v*)&trw[(ni * 16 + l15) * 72 + mi * 16 + l16 * 4] = p;
      }
    wave_transposed_store(Ct, ct_stride, trw, (m0 + wm) >> 8, (m0 + wm) & 255, wn,
                          lane);
  }
}

// ---------------- per-chunk kv[e][h] = sum_c vT[e][c]*lkT[h][c] ----------------
__global__ __launch_bounds__(256) void kv_kernel(const u16* __restrict__ vT,
                                                 const u16* __restrict__ lkT,
                                                 u16* __restrict__ kv) {
  const int chunk = blockIdx.y;
  const int et = blockIdx.x;  // e-block of 128
  const int w = threadIdx.x >> 6, lane = threadIdx.x & 63;
  const int l15 = lane & 15, l16 = lane >> 4;
  const size_t vb = (size_t)chunk * (2048 * 256) + (size_t)et * (128 * 256);
  const size_t lb = (size_t)chunk * (128 * 256);
  const int we = (w >> 1) * 64, wh = (w & 1) * 64;
  floatx4 acc[4][4];
#pragma unroll
  for (int i = 0; i < 4; ++i)
#pragma unroll
    for (int j = 0; j < 4; ++j) acc[i][j] = fzero();
  for (int kk = 0; kk < 8; ++kk) {
    short8 av[4], bv[4];
#pragma unroll
    for (int mi = 0; mi < 4; ++mi)
      av[mi] = *(const short8*)&vT[vb + (size_t)(we + mi * 16 + l15) * 256 + kk * 32 +
                                   l16 * 8];
#pragma unroll
    for (int ni = 0; ni < 4; ++ni)
      bv[ni] = *(const short8*)&lkT[lb + (size_t)(wh + ni * 16 + l15) * 256 + kk * 32 +
                                    l16 * 8];
#pragma unroll
    for (int mi = 0; mi < 4; ++mi)
#pragma unroll
      for (int ni = 0; ni < 4; ++ni) acc[mi][ni] = mfma16(av[mi], bv[ni], acc[mi][ni]);
  }
  u16* out = kv + (size_t)chunk * (2048 * 128);
#pragma unroll
  for (int mi = 0; mi < 4; ++mi)
#pragma unroll
    for (int ni = 0; ni < 4; ++ni) {
      const int h = wh + ni * 16 + l15;
      const int e = et * 128 + we + mi * 16 + l16 * 4;
#pragma unroll
      for (int r = 0; r < 4; ++r) out[(size_t)(e + r) * 128 + h] = f2bf(acc[mi][ni][r]);
    }
}

// ---------------- exclusive cumsum over chunks (in place, bf16) ----------------
__global__ __launch_bounds__(256) void cumsum_kernel(u16* __restrict__ kv) {
  const int idx = blockIdx.x * 256 + threadIdx.x;  // 0..262143 (= 2048*128)
  const int b = blockIdx.y;
  float s = 0.f;
  for (int g = 0; g < 16; ++g) {
    const size_t a = (size_t)(b * 16 + g) * 262144 + idx;
    const float v = bf2f(kv[a]);
    kv[a] = f2bf(s);
    s += v;
  }
}

// ---------------- fused chunk attention ----------------
__global__ __launch_bounds__(256) void attn_kernel(
    const u16* __restrict__ qq, const u16* __restrict__ qk, const u16* __restrict__ lq,
    const u16* __restrict__ vT, const u16* __restrict__ kvT,
    u16* __restrict__ gate_op) {
  __shared__ u16 S[64][264];
  const int chunk = blockIdx.y;
  const int e0 = blockIdx.x * 256;
  const int tok0 = chunk * 256;
  const int w = threadIdx.x >> 6, lane = threadIdx.x & 63;
  const int l15 = lane & 15, l16 = lane >> 4;
  const float isc = 0.022097086912079608f;  // 1/sqrt(2048)
  const size_t vbase = (size_t)chunk * (2048 * 256);
  const size_t kbase = (size_t)chunk * (2048 * 128);
  const int ew = e0 + w * 64;

  for (int ns = 0; ns < 4; ++ns) {
    // ---- phase 1: S rows [ns*64+w*16, +16) = relu^2(mask(qq*qk^T/scale))
    const int r0 = ns * 64 + w * 16;
    short8 af[4];
#pragma unroll
    for (int kk = 0; kk < 4; ++kk)
      af[kk] = *(const short8*)&qq[(size_t)(tok0 + r0 + l15) * 128 + kk * 32 + l16 * 8];
    const int mt_cnt = (r0 >> 4) + 1;   // tiles with any unmasked entry
    const int mt_all = (ns + 1) * 4;    // tiles phase 2 will read
    const int srow = w * 16 + l16 * 4;
    for (int mt = 0; mt < mt_all; ++mt) {
      if (mt < mt_cnt) {
        floatx4 a = fzero();
#pragma unroll
        for (int kk = 0; kk < 4; ++kk) {
          short8 bq =
              *(const short8*)&qk[(size_t)(tok0 + mt * 16 + l15) * 128 + kk * 32 +
                                  l16 * 8];
          a = mfma16(af[kk], bq, a);
        }
        const int mcol = mt * 16 + l15;
#pragma unroll
        for (int r = 0; r < 4; ++r) {
          const int nrow = r0 + l16 * 4 + r;
          float sv = a[r] * isc;
          sv = (mcol <= nrow) ? sv : 0.f;
          sv = fmaxf(sv, 0.f);
          S[srow + r][mcol] = f2bf(sv * sv);
        }
      } else {
#pragma unroll
        for (int r = 0; r < 4; ++r) S[srow + r][mt * 16 + l15] = (u16)0;
      }
    }
    __syncthreads();

    // ---- phase 2: (S@v + lin_q@kv) * gate, wave covers e cols [ew, ew+64)
    floatx4 acc[4][4];
#pragma unroll
    for (int i = 0; i < 4; ++i)
#pragma unroll
      for (int j = 0; j < 4; ++j) acc[i][j] = fzero();

    const int ks = (ns + 1) * 2;  // causal truncation of K range
    for (int kk = 0; kk < ks; ++kk) {
      short8 sa[4];
#pragma unroll
      for (int nt = 0; nt < 4; ++nt)
        sa[nt] = *(const short8*)&S[nt * 16 + l15][kk * 32 + l16 * 8];
#pragma unroll
      for (int ei = 0; ei < 4; ++ei) {
        short8 vb = *(const short8*)&vT[vbase + (size_t)(ew + ei * 16 + l15) * 256 +
                                        kk * 32 + l16 * 8];
#pragma unroll
        for (int nt = 0; nt < 4; ++nt) acc[nt][ei] = mfma16(sa[nt], vb, acc[nt][ei]);
      }
    }
#pragma unroll
    for (int kk = 0; kk < 4; ++kk) {
      short8 la[4];
#pragma unroll
      for (int nt = 0; nt < 4; ++nt)
        la[nt] = *(const short8*)&lq[(size_t)(tok0 + ns * 64 + nt * 16 + l15) * 128 +
                                     kk * 32 + l16 * 8];
#pragma unroll
      for (int ei = 0; ei < 4; ++ei) {
        short8 kb = *(const short8*)&kvT[kbase + (size_t)(ew + ei * 16 + l15) * 128 +
                                         kk * 32 + l16 * 8];
#pragma unroll
        for (int nt = 0; nt < 4; ++nt) acc[nt][ei] = mfma16(la[nt], kb, acc[nt][ei]);
      }
    }
#pragma unroll
    for (int nt = 0; nt < 4; ++nt)
#pragma unroll
      for (int ei = 0; ei < 4; ++ei) {
        const int e_g = ew + ei * 16 + l15;
        const int nb = tok0 + ns * 64 + nt * 16 + l16 * 4;
#pragma unroll
        for (int r = 0; r < 4; ++r) {
          const size_t ad = (size_t)(nb + r) * 2048 + e_g;
          const float gv = bf2f(gate_op[ad]);
          gate_op[ad] = f2bf(acc[nt][ei][r] * gv);
        }
      }
    __syncthreads();
  }
}

extern "C" void kernel_launch(void* const* d_in, const int* in_sizes, int n_in,
                              void* d_out, int out_size, void* d_ws, size_t ws_size,
                              hipStream_t stream) {
  (void)in_sizes; (void)n_in; (void)out_size; (void)ws_size;
  const float* x = (const float*)d_in[0];
  const float* Wv = (const float*)d_in[1];
  const float* bv = (const float*)d_in[2];
  const float* Wg = (const float*)d_in[3];
  const float* bg = (const float*)d_in[4];
  const float* Win = (const float*)d_in[5];
  const float* bin = (const float*)d_in[6];
  const float* Wout = (const float*)d_in[7];
  const float* bout = (const float*)d_in[8];
  const float* gqq = (const float*)d_in[9];
  const float* bqq = (const float*)d_in[10];
  const float* gqk = (const float*)d_in[11];
  const float* bqk = (const float*)d_in[12];
  const float* glq = (const float*)d_in[13];
  const float* blq = (const float*)d_in[14];
  const float* glk = (const float*)d_in[15];
  const float* blk = (const float*)d_in[16];

  char* p = (char*)d_ws;
  u16* xb = (u16*)p;   p += (size_t)16384 * 1024 * 2;
  u16* wvT = (u16*)p;  p += (size_t)2048 * 1024 * 2;
  u16* wgT = (u16*)p;  p += (size_t)2048 * 1024 * 2;
  u16* winT = (u16*)p; p += (size_t)128 * 1024 * 2;
  u16* woT = (u16*)p;  p += (size_t)1024 * 2048 * 2;
  u16* vTb = (u16*)p;  p += (size_t)64 * 2048 * 256 * 2;
  u16* gate = (u16*)p; p += (size_t)16384 * 2048 * 2;  // gate, then op (in place)
  u16* qqb = (u16*)p;  p += (size_t)16384 * 128 * 2;
  u16* qkb = (u16*)p;  p += (size_t)16384 * 128 * 2;
  u16* lqb = (u16*)p;  p += (size_t)16384 * 128 * 2;
  u16* lkTb = (u16*)p; p += (size_t)64 * 128 * 256 * 2;
  u16* kvb = (u16*)p;  p += (size_t)64 * 2048 * 128 * 2;

  cast_x_kernel<<<16384, 256, 0, stream>>>(x, xb, 4194304);
  transpose_cast_kernel<<<dim3(64, 32), 256, 0, stream>>>(Wv, wvT, 1024, 2048);
  transpose_cast_kernel<<<dim3(64, 32), 256, 0, stream>>>(Wg, wgT, 1024, 2048);
  transpose_cast_kernel<<<dim3(4, 32), 256, 0, stream>>>(Win, winT, 1024, 128);
  transpose_cast_kernel<<<dim3(32, 64), 256, 0, stream>>>(Wout, woT, 2048, 1024);

  gemm_bt<1><<<dim3(16, 128), 256, 0, stream>>>(
      xb, wvT, 16384, 2048, 1024, bv, nullptr, nullptr, vTb, 2048L * 256, nullptr,
      nullptr, nullptr, nullptr, nullptr, nullptr, nullptr, nullptr, nullptr, nullptr);
  gemm_bt<0><<<dim3(16, 128), 256, 0, stream>>>(
      xb, wgT, 16384, 2048, 1024, bg, gate, nullptr, nullptr, 0, nullptr, nullptr,
      nullptr, nullptr, nullptr, nullptr, nullptr, nullptr, nullptr, nullptr);
  gemm_bt<2><<<dim3(1, 128), 256, 0, stream>>>(
      xb, winT, 16384, 128, 1024, bin, qqb, nullptr, lkTb, 128L * 256, qkb, lqb, gqq,
      bqq, gqk, bqk, glq, blq, glk, blk);

  kv_kernel<<<dim3(16, 64), 256, 0, stream>>>(vTb, lkTb, kvb);
  cumsum_kernel<<<dim3(1024, 4), 256, 0, stream>>>(kvb);
  attn_kernel<<<dim3(8, 64), 256, 0, stream>>>(qqb, qkb, lqb, vTb, kvb, gate);

  gemm_bt<3><<<dim3(8, 128), 256, 0, stream>>>(
      gate, woT, 16384, 1024, 2048, bout, nullptr, (float*)d_out, nullptr, 0, nullptr,
      nullptr, nullptr, nullptr, nullptr, nullptr, nullptr, nullptr, nullptr, nullptr);
}

// Round 2
// 658.002 us; speedup vs baseline: 1.0211x; 1.0211x over previous
//
#include <hip/hip_runtime.h>

typedef __attribute__((ext_vector_type(8))) short short8;
typedef __attribute__((ext_vector_type(4))) float floatx4;
typedef __attribute__((ext_vector_type(4))) unsigned short ushort4v;
typedef unsigned short u16;

#define DEV __device__ __forceinline__

DEV u16 f2bf(float f) {
  unsigned int u = __float_as_uint(f);
  u += 0x7fffu + ((u >> 16) & 1u);
  return (u16)(u >> 16);
}
DEV float bf2f(u16 h) { return __uint_as_float(((unsigned int)h) << 16); }
DEV float silu_f(float x) { return x / (1.f + __expf(-x)); }
DEV floatx4 fzero() { floatx4 z = {0.f, 0.f, 0.f, 0.f}; return z; }
DEV floatx4 mfma16(short8 a, short8 b, floatx4 c) {
  return __builtin_amdgcn_mfma_f32_16x16x32_bf16(a, b, c, 0, 0, 0);
}
DEV void gll16(const void* g, void* l) {
  __builtin_amdgcn_global_load_lds((__attribute__((address_space(1))) void*)g,
                                   (__attribute__((address_space(3))) void*)l,
                                   16, 0, 0);
}

// ---------------- cast x (f32 -> bf16) ----------------
__global__ __launch_bounds__(256) void cast_x_kernel(const float* __restrict__ x,
                                                     u16* __restrict__ xb, int n4) {
  int i = blockIdx.x * 256 + threadIdx.x;
  if (i >= n4) return;
  float4 v = ((const float4*)x)[i];
  ushort4v o;
  o[0] = f2bf(v.x); o[1] = f2bf(v.y); o[2] = f2bf(v.z); o[3] = f2bf(v.w);
  *(ushort4v*)&xb[(size_t)i * 4] = o;
}

// ---------------- transpose+cast: W[K][N] f32 -> WT[N][K] bf16 ----------------
__global__ __launch_bounds__(256) void transpose_cast_kernel(const float* __restrict__ W,
                                                             u16* __restrict__ WT,
                                                             int K, int N) {
  __shared__ u16 tile[32][36];
  int n0 = blockIdx.x * 32, k0 = blockIdx.y * 32;
  int t = threadIdx.x;
  int r = t >> 3, cs = (t & 7) * 4;
  float4 v = *(const float4*)&W[(size_t)(k0 + r) * N + n0 + cs];
  tile[r][cs + 0] = f2bf(v.x);
  tile[r][cs + 1] = f2bf(v.y);
  tile[r][cs + 2] = f2bf(v.z);
  tile[r][cs + 3] = f2bf(v.w);
  __syncthreads();
  ushort4v o;
  o[0] = tile[cs + 0][r];
  o[1] = tile[cs + 1][r];
  o[2] = tile[cs + 2][r];
  o[3] = tile[cs + 3][r];
  *(ushort4v*)&WT[(size_t)(n0 + r) * K + k0 + cs] = o;
}

// ---------------- transposed bf16 store helper (wave 64x64 tile in tr[64][72]) ----
DEV void wave_transposed_store(u16* __restrict__ Ct, long chunk_stride,
                               const u16* trw, int chunk, int cbase, int nbase,
                               int lane) {
#pragma unroll
  for (int it = 0; it < 8; ++it) {
    int e_l = it * 8 + (lane >> 3);
    int c_off = (lane & 7) * 8;
    short8 val = *(const short8*)&trw[e_l * 72 + c_off];
    *(short8*)&Ct[(size_t)chunk * chunk_stride + (size_t)(nbase + e_l) * 256 + cbase +
                  c_off] = val;
  }
}

// ---------------- GEMM: C = A[M,K] * Bt[N,K]^T, bf16 MFMA, 128x128x32 ----------
// LDS staging is XOR-swizzled: LDS[row][p] holds global k-chunk p ^ ((row>>1)&3)
// so fragment ds_read_b128 is 2-way (free) instead of 8-way bank-aliased.
// MODE 0: silu -> bf16 natural (gate), coalesced via LDS transpose
// MODE 1: silu -> bf16 transposed per-chunk (vT)
// MODE 2: silu -> qq/qk/lq natural (affine) + lkT transposed (affine)
// MODE 3: +bias -> fp32 natural (final output)
template <int MODE>
__global__ __launch_bounds__(256) void gemm_bt(
    const u16* __restrict__ A, const u16* __restrict__ Bt, int M, int N, int K,
    const float* __restrict__ bias, u16* __restrict__ Cn, float* __restrict__ Cf,
    u16* __restrict__ Ct, long ct_stride, u16* __restrict__ Cn2, u16* __restrict__ Cn3,
    const float* __restrict__ gqq, const float* __restrict__ bqq,
    const float* __restrict__ gqk, const float* __restrict__ bqk,
    const float* __restrict__ glq, const float* __restrict__ blq,
    const float* __restrict__ glk, const float* __restrict__ blk) {
  __shared__ union {
    struct { u16 a[128 * 32]; u16 b[128 * 32]; } st;
    u16 tr[4 * 64 * 72];
  } sm;
  const int t = threadIdx.x;
  const int wave = t >> 6, lane = t & 63;
  const int l15 = lane & 15, l16 = lane >> 4;
  const int n0 = blockIdx.x * 128, m0 = blockIdx.y * 128;
  const int wm = (wave >> 1) * 64, wn = (wave & 1) * 64;

  floatx4 acc[4][4];
#pragma unroll
  for (int i = 0; i < 4; ++i)
#pragma unroll
    for (int j = 0; j < 4; ++j) acc[i][j] = fzero();

  const int c0 = t, c1 = 256 + t;
  const int r0s = c0 >> 2, p0s = c0 & 3;
  const int r1s = c1 >> 2, p1s = c1 & 3;
  const int g0 = p0s ^ ((r0s >> 1) & 3);  // swizzled global k-chunk
  const int g1 = p1s ^ ((r1s >> 1) & 3);
  const u16* pa0 = A + (size_t)(m0 + r0s) * K + g0 * 8;
  const u16* pa1 = A + (size_t)(m0 + r1s) * K + g1 * 8;
  const u16* pb0 = Bt + (size_t)(n0 + r0s) * K + g0 * 8;
  const u16* pb1 = Bt + (size_t)(n0 + r1s) * K + g1 * 8;
  const int sw = (l15 >> 1) & 3;  // fragment-read swizzle (same for A and B rows)

  for (int k0 = 0; k0 < K; k0 += 32) {
    __syncthreads();
    gll16(pa0 + k0, &sm.st.a[c0 * 8]);
    gll16(pa1 + k0, &sm.st.a[c1 * 8]);
    gll16(pb0 + k0, &sm.st.b[c0 * 8]);
    gll16(pb1 + k0, &sm.st.b[c1 * 8]);
    __syncthreads();
    short8 af[4], bfr[4];
#pragma unroll
    for (int mi = 0; mi < 4; ++mi)
      af[mi] = *(const short8*)&sm.st.a[(wm + mi * 16 + l15) * 32 + (l16 ^ sw) * 8];
#pragma unroll
    for (int ni = 0; ni < 4; ++ni)
      bfr[ni] = *(const short8*)&sm.st.b[(wn + ni * 16 + l15) * 32 + (l16 ^ sw) * 8];
#pragma unroll
    for (int mi = 0; mi < 4; ++mi)
#pragma unroll
      for (int ni = 0; ni < 4; ++ni)
        acc[mi][ni] = mfma16(af[mi], bfr[ni], acc[mi][ni]);
  }
  __syncthreads();

  if constexpr (MODE == 0) {
    u16* trw = &sm.tr[wave * 64 * 72];
#pragma unroll
    for (int mi = 0; mi < 4; ++mi)
#pragma unroll
      for (int ni = 0; ni < 4; ++ni) {
        const int col = n0 + wn + ni * 16 + l15;
        const float bc = bias[col];
#pragma unroll
        for (int r = 0; r < 4; ++r)
          trw[(mi * 16 + l16 * 4 + r) * 72 + ni * 16 + l15] =
              f2bf(silu_f(acc[mi][ni][r] + bc));
      }
#pragma unroll
    for (int it = 0; it < 8; ++it) {
      const int m_l = it * 8 + (lane >> 3);
      const int n_off = (lane & 7) * 8;
      *(short8*)&Cn[(size_t)(m0 + wm + m_l) * N + n0 + wn + n_off] =
          *(const short8*)&trw[m_l * 72 + n_off];
    }
  } else if constexpr (MODE == 3) {
#pragma unroll
    for (int mi = 0; mi < 4; ++mi)
#pragma unroll
      for (int ni = 0; ni < 4; ++ni) {
        const int col = n0 + wn + ni * 16 + l15;
        const float bc = bias[col];
        const int row = m0 + wm + mi * 16 + l16 * 4;
#pragma unroll
        for (int r = 0; r < 4; ++r)
          Cf[(size_t)(row + r) * N + col] = acc[mi][ni][r] + bc;
      }
  } else if constexpr (MODE == 1) {
    u16* trw = &sm.tr[wave * 64 * 72];
#pragma unroll
    for (int mi = 0; mi < 4; ++mi)
#pragma unroll
      for (int ni = 0; ni < 4; ++ni) {
        const int col = n0 + wn + ni * 16 + l15;
        const float bc = bias[col];
        ushort4v p;
#pragma unroll
        for (int r = 0; r < 4; ++r) p[r] = f2bf(silu_f(acc[mi][ni][r] + bc));
        *(ushort4v*)&trw[(ni * 16 + l15) * 72 + mi * 16 + l16 * 4] = p;
      }
    wave_transposed_store(Ct, ct_stride, trw, (m0 + wm) >> 8, (m0 + wm) & 255,
                          n0 + wn, lane);
  } else {  // MODE 2
    u16* trw = &sm.tr[wave * 64 * 72];
#pragma unroll
    for (int mi = 0; mi < 4; ++mi)
#pragma unroll
      for (int ni = 0; ni < 4; ++ni) {
        const int col = wn + ni * 16 + l15;
        const float bc = bias[col];
        const float Gqq = gqq[col], Bqq = bqq[col];
        const float Gqk = gqk[col], Bqk = bqk[col];
        const float Glq = glq[col], Blq = blq[col];
        const float Glk = glk[col], Blk = blk[col];
        const int row = m0 + wm + mi * 16 + l16 * 4;
        ushort4v p;
#pragma unroll
        for (int r = 0; r < 4; ++r) {
          const float sv = silu_f(acc[mi][ni][r] + bc);
          const size_t ad = (size_t)(row + r) * N + col;
          Cn[ad] = f2bf(sv * Gqq + Bqq);
          Cn2[ad] = f2bf(sv * Gqk + Bqk);
          Cn3[ad] = f2bf(sv * Glq + Blq);
          p[r] = f2bf(sv * Glk + Blk);
        }
        *(ushort4v*)&trw[(ni * 16 + l15) * 72 + mi * 16 + l16 * 4] = p;
      }
    wave_transposed_store(Ct, ct_stride, trw, (m0 + wm) >> 8, (m0 + wm) & 255, wn,
                          lane);
  }
}

// ---------------- per-chunk kv[e][h] = sum_c vT[e][c]*lkT[h][c] ----------------
__global__ __launch_bounds__(256) void kv_kernel(const u16* __restrict__ vT,
                                                 const u16* __restrict__ lkT,
                                                 u16* __restrict__ kv) {
  const int chunk = blockIdx.y;
  const int et = blockIdx.x;  // e-block of 128
  const int w = threadIdx.x >> 6, lane = threadIdx.x & 63;
  const int l15 = lane & 15, l16 = lane >> 4;
  const size_t vb = (size_t)chunk * (2048 * 256) + (size_t)et * (128 * 256);
  const size_t lb = (size_t)chunk * (128 * 256);
  const int we = (w >> 1) * 64, wh = (w & 1) * 64;
  floatx4 acc[4][4];
#pragma unroll
  for (int i = 0; i < 4; ++i)
#pragma unroll
    for (int j = 0; j < 4; ++j) acc[i][j] = fzero();
  for (int kk = 0; kk < 8; ++kk) {
    short8 av[4], bv[4];
#pragma unroll
    for (int mi = 0; mi < 4; ++mi)
      av[mi] = *(const short8*)&vT[vb + (size_t)(we + mi * 16 + l15) * 256 + kk * 32 +
                                   l16 * 8];
#pragma unroll
    for (int ni = 0; ni < 4; ++ni)
      bv[ni] = *(const short8*)&lkT[lb + (size_t)(wh + ni * 16 + l15) * 256 + kk * 32 +
                                    l16 * 8];
#pragma unroll
    for (int mi = 0; mi < 4; ++mi)
#pragma unroll
      for (int ni = 0; ni < 4; ++ni) acc[mi][ni] = mfma16(av[mi], bv[ni], acc[mi][ni]);
  }
  u16* out = kv + (size_t)chunk * (2048 * 128);
#pragma unroll
  for (int mi = 0; mi < 4; ++mi)
#pragma unroll
    for (int ni = 0; ni < 4; ++ni) {
      const int h = wh + ni * 16 + l15;
      const int e = et * 128 + we + mi * 16 + l16 * 4;
#pragma unroll
      for (int r = 0; r < 4; ++r) out[(size_t)(e + r) * 128 + h] = f2bf(acc[mi][ni][r]);
    }
}

// ---------------- exclusive cumsum over chunks (in place, bf16) ----------------
__global__ __launch_bounds__(256) void cumsum_kernel(u16* __restrict__ kv) {
  const int idx = blockIdx.x * 256 + threadIdx.x;  // 0..262143 (= 2048*128)
  const int b = blockIdx.y;
  float s = 0.f;
  for (int g = 0; g < 16; ++g) {
    const size_t a = (size_t)(b * 16 + g) * 262144 + idx;
    const float v = bf2f(kv[a]);
    kv[a] = f2bf(s);
    s += v;
  }
}

// ---------------- fused chunk attention ----------------
__global__ __launch_bounds__(256) void attn_kernel(
    const u16* __restrict__ qq, const u16* __restrict__ qk, const u16* __restrict__ lq,
    const u16* __restrict__ vT, const u16* __restrict__ kvT,
    u16* __restrict__ gate_op) {
  __shared__ u16 S[64][264];
  const int chunk = blockIdx.y;
  const int e0 = blockIdx.x * 256;
  const int tok0 = chunk * 256;
  const int w = threadIdx.x >> 6, lane = threadIdx.x & 63;
  const int l15 = lane & 15, l16 = lane >> 4;
  const float isc = 0.022097086912079608f;  // 1/sqrt(2048)
  const size_t vbase = (size_t)chunk * (2048 * 256);
  const size_t kbase = (size_t)chunk * (2048 * 128);
  const int ew = e0 + w * 64;

  for (int ns = 0; ns < 4; ++ns) {
    // ---- phase 1: S rows [ns*64+w*16, +16) = relu^2(mask(qq*qk^T/scale))
    const int r0 = ns * 64 + w * 16;
    short8 af[4];
#pragma unroll
    for (int kk = 0; kk < 4; ++kk)
      af[kk] = *(const short8*)&qq[(size_t)(tok0 + r0 + l15) * 128 + kk * 32 + l16 * 8];
    const int mt_cnt = (r0 >> 4) + 1;   // tiles with any unmasked entry
    const int mt_all = (ns + 1) * 4;    // tiles phase 2 will read
    const int srow = w * 16 + l16 * 4;
    for (int mt = 0; mt < mt_all; ++mt) {
      if (mt < mt_cnt) {
        floatx4 a = fzero();
#pragma unroll
        for (int kk = 0; kk < 4; ++kk) {
          short8 bq =
              *(const short8*)&qk[(size_t)(tok0 + mt * 16 + l15) * 128 + kk * 32 +
                                  l16 * 8];
          a = mfma16(af[kk], bq, a);
        }
        const int mcol = mt * 16 + l15;
#pragma unroll
        for (int r = 0; r < 4; ++r) {
          const int nrow = r0 + l16 * 4 + r;
          float sv = a[r] * isc;
          sv = (mcol <= nrow) ? sv : 0.f;
          sv = fmaxf(sv, 0.f);
          S[srow + r][mcol] = f2bf(sv * sv);
        }
      } else {
#pragma unroll
        for (int r = 0; r < 4; ++r) S[srow + r][mt * 16 + l15] = (u16)0;
      }
    }
    __syncthreads();

    // ---- phase 2: (S@v + lin_q@kv) * gate, wave covers e cols [ew, ew+64)
    floatx4 acc[4][4];
#pragma unroll
    for (int i = 0; i < 4; ++i)
#pragma unroll
      for (int j = 0; j < 4; ++j) acc[i][j] = fzero();

    const int ks = (ns + 1) * 2;  // causal truncation of K range
    for (int kk = 0; kk < ks; ++kk) {
      short8 sa[4];
#pragma unroll
      for (int nt = 0; nt < 4; ++nt)
        sa[nt] = *(const short8*)&S[nt * 16 + l15][kk * 32 + l16 * 8];
#pragma unroll
      for (int ei = 0; ei < 4; ++ei) {
        short8 vb = *(const short8*)&vT[vbase + (size_t)(ew + ei * 16 + l15) * 256 +
                                        kk * 32 + l16 * 8];
#pragma unroll
        for (int nt = 0; nt < 4; ++nt) acc[nt][ei] = mfma16(sa[nt], vb, acc[nt][ei]);
      }
    }
#pragma unroll
    for (int kk = 0; kk < 4; ++kk) {
      short8 la[4];
#pragma unroll
      for (int nt = 0; nt < 4; ++nt)
        la[nt] = *(const short8*)&lq[(size_t)(tok0 + ns * 64 + nt * 16 + l15) * 128 +
                                     kk * 32 + l16 * 8];
#pragma unroll
      for (int ei = 0; ei < 4; ++ei) {
        short8 kb = *(const short8*)&kvT[kbase + (size_t)(ew + ei * 16 + l15) * 128 +
                                         kk * 32 + l16 * 8];
#pragma unroll
        for (int nt = 0; nt < 4; ++nt) acc[nt][ei] = mfma16(la[nt], kb, acc[nt][ei]);
      }
    }
#pragma unroll
    for (int nt = 0; nt < 4; ++nt)
#pragma unroll
      for (int ei = 0; ei < 4; ++ei) {
        const int e_g = ew + ei * 16 + l15;
        const int nb = tok0 + ns * 64 + nt * 16 + l16 * 4;
#pragma unroll
        for (int r = 0; r < 4; ++r) {
          const size_t ad = (size_t)(nb + r) * 2048 + e_g;
          const float gv = bf2f(gate_op[ad]);
          gate_op[ad] = f2bf(acc[nt][ei][r] * gv);
        }
      }
    __syncthreads();
  }
}

extern "C" void kernel_launch(void* const* d_in, const int* in_sizes, int n_in,
                              void* d_out, int out_size, void* d_ws, size_t ws_size,
                              hipStream_t stream) {
  (void)in_sizes; (void)n_in; (void)out_size; (void)ws_size;
  const float* x = (const float*)d_in[0];
  const float* Wv = (const float*)d_in[1];
  const float* bv = (const float*)d_in[2];
  const float* Wg = (const float*)d_in[3];
  const float* bg = (const float*)d_in[4];
  const float* Win = (const float*)d_in[5];
  const float* bin = (const float*)d_in[6];
  const float* Wout = (const float*)d_in[7];
  const float* bout = (const float*)d_in[8];
  const float* gqq = (const float*)d_in[9];
  const float* bqq = (const float*)d_in[10];
  const float* gqk = (const float*)d_in[11];
  const float* bqk = (const float*)d_in[12];
  const float* glq = (const float*)d_in[13];
  const float* blq = (const float*)d_in[14];
  const float* glk = (const float*)d_in[15];
  const float* blk = (const float*)d_in[16];

  char* p = (char*)d_ws;
  u16* xb = (u16*)p;   p += (size_t)16384 * 1024 * 2;
  u16* wvT = (u16*)p;  p += (size_t)2048 * 1024 * 2;
  u16* wgT = (u16*)p;  p += (size_t)2048 * 1024 * 2;
  u16* winT = (u16*)p; p += (size_t)128 * 1024 * 2;
  u16* woT = (u16*)p;  p += (size_t)1024 * 2048 * 2;
  u16* vTb = (u16*)p;  p += (size_t)64 * 2048 * 256 * 2;
  u16* gate = (u16*)p; p += (size_t)16384 * 2048 * 2;  // gate, then op (in place)
  u16* qqb = (u16*)p;  p += (size_t)16384 * 128 * 2;
  u16* qkb = (u16*)p;  p += (size_t)16384 * 128 * 2;
  u16* lqb = (u16*)p;  p += (size_t)16384 * 128 * 2;
  u16* lkTb = (u16*)p; p += (size_t)64 * 128 * 256 * 2;
  u16* kvb = (u16*)p;  p += (size_t)64 * 2048 * 128 * 2;

  cast_x_kernel<<<16384, 256, 0, stream>>>(x, xb, 4194304);
  transpose_cast_kernel<<<dim3(64, 32), 256, 0, stream>>>(Wv, wvT, 1024, 2048);
  transpose_cast_kernel<<<dim3(64, 32), 256, 0, stream>>>(Wg, wgT, 1024, 2048);
  transpose_cast_kernel<<<dim3(4, 32), 256, 0, stream>>>(Win, winT, 1024, 128);
  transpose_cast_kernel<<<dim3(32, 64), 256, 0, stream>>>(Wout, woT, 2048, 1024);

  gemm_bt<1><<<dim3(16, 128), 256, 0, stream>>>(
      xb, wvT, 16384, 2048, 1024, bv, nullptr, nullptr, vTb, 2048L * 256, nullptr,
      nullptr, nullptr, nullptr, nullptr, nullptr, nullptr, nullptr, nullptr, nullptr);
  gemm_bt<0><<<dim3(16, 128), 256, 0, stream>>>(
      xb, wgT, 16384, 2048, 1024, bg, gate, nullptr, nullptr, 0, nullptr, nullptr,
      nullptr, nullptr, nullptr, nullptr, nullptr, nullptr, nullptr, nullptr);
  gemm_bt<2><<<dim3(1, 128), 256, 0, stream>>>(
      xb, winT, 16384, 128, 1024, bin, qqb, nullptr, lkTb, 128L * 256, qkb, lqb, gqq,
      bqq, gqk, bqk, glq, blq, glk, blk);

  kv_kernel<<<dim3(16, 64), 256, 0, stream>>>(vTb, lkTb, kvb);
  cumsum_kernel<<<dim3(1024, 4), 256, 0, stream>>>(kvb);
  attn_kernel<<<dim3(8, 64), 256, 0, stream>>>(qqb, qkb, lqb, vTb, kvb, gate);

  gemm_bt<3><<<dim3(8, 128), 256, 0, stream>>>(
      gate, woT, 16384, 1024, 2048, bout, nullptr, (float*)d_out, nullptr, 0, nullptr,
      nullptr, nullptr, nullptr, nullptr, nullptr, nullptr, nullptr, nullptr, nullptr);
}

// Round 3
// 601.642 us; speedup vs baseline: 1.1168x; 1.0937x over previous
//
#include <hip/hip_runtime.h>

typedef __attribute__((ext_vector_type(8))) short short8;
typedef __attribute__((ext_vector_type(4))) float floatx4;
typedef __attribute__((ext_vector_type(4))) unsigned short ushort4v;
typedef unsigned short u16;

#define DEV __device__ __forceinline__

DEV u16 f2bf(float f) {
  unsigned int u = __float_as_uint(f);
  u += 0x7fffu + ((u >> 16) & 1u);
  return (u16)(u >> 16);
}
DEV float bf2f(u16 h) { return __uint_as_float(((unsigned int)h) << 16); }
DEV float silu_f(float x) { return x / (1.f + __expf(-x)); }
DEV floatx4 fzero() { floatx4 z = {0.f, 0.f, 0.f, 0.f}; return z; }
DEV floatx4 mfma16(short8 a, short8 b, floatx4 c) {
  return __builtin_amdgcn_mfma_f32_16x16x32_bf16(a, b, c, 0, 0, 0);
}
DEV void gll16(const void* g, void* l) {
  __builtin_amdgcn_global_load_lds((__attribute__((address_space(1))) void*)g,
                                   (__attribute__((address_space(3))) void*)l,
                                   16, 0, 0);
}

// ---------------- cast x (f32 -> bf16) ----------------
__global__ __launch_bounds__(256) void cast_x_kernel(const float* __restrict__ x,
                                                     u16* __restrict__ xb, int n4) {
  int i = blockIdx.x * 256 + threadIdx.x;
  if (i >= n4) return;
  float4 v = ((const float4*)x)[i];
  ushort4v o;
  o[0] = f2bf(v.x); o[1] = f2bf(v.y); o[2] = f2bf(v.z); o[3] = f2bf(v.w);
  *(ushort4v*)&xb[(size_t)i * 4] = o;
}

// ---------------- transpose+cast: W[K][N] f32 -> WT[N][K] bf16 ----------------
__global__ __launch_bounds__(256) void transpose_cast_kernel(const float* __restrict__ W,
                                                             u16* __restrict__ WT,
                                                             int K, int N) {
  __shared__ u16 tile[32][36];
  int n0 = blockIdx.x * 32, k0 = blockIdx.y * 32;
  int t = threadIdx.x;
  int r = t >> 3, cs = (t & 7) * 4;
  float4 v = *(const float4*)&W[(size_t)(k0 + r) * N + n0 + cs];
  tile[r][cs + 0] = f2bf(v.x);
  tile[r][cs + 1] = f2bf(v.y);
  tile[r][cs + 2] = f2bf(v.z);
  tile[r][cs + 3] = f2bf(v.w);
  __syncthreads();
  ushort4v o;
  o[0] = tile[cs + 0][r];
  o[1] = tile[cs + 1][r];
  o[2] = tile[cs + 2][r];
  o[3] = tile[cs + 3][r];
  *(ushort4v*)&WT[(size_t)(n0 + r) * K + k0 + cs] = o;
}

// ---------------- transposed bf16 store helper (wave 64x64 tile in tr[64][72]) ----
DEV void wave_transposed_store(u16* __restrict__ Ct, long chunk_stride,
                               const u16* trw, int chunk, int cbase, int nbase,
                               int lane) {
#pragma unroll
  for (int it = 0; it < 8; ++it) {
    int e_l = it * 8 + (lane >> 3);
    int c_off = (lane & 7) * 8;
    short8 val = *(const short8*)&trw[e_l * 72 + c_off];
    *(short8*)&Ct[(size_t)chunk * chunk_stride + (size_t)(nbase + e_l) * 256 + cbase +
                  c_off] = val;
  }
}

// ---------------- GEMM: C = A[M,K] * Bt[N,K]^T, bf16 MFMA, 128x128, BK=64 ------
// LDS rows are 128 B (64 k-elems = 8 chunks of 16 B); chunk position p in row r
// holds global chunk p ^ (r&7): fragment ds_read_b128 spreads the 8 bank-quads
// uniformly (8 lanes/quad = the 1 KB minimum, conflict-free).
// 1-D grid with XCD-aware remap: ell&7 selects the XCD-slab of 16 m-tiles so
// each per-XCD L2 fetches its A slice exactly once.
// MODE 0: silu -> bf16 natural (gate), coalesced via LDS transpose
// MODE 1: silu -> bf16 transposed per-chunk (vT)
// MODE 2: silu -> qq/qk/lq natural (affine) + lkT transposed (affine)
// MODE 3: +bias -> fp32 natural (final output)
template <int MODE>
__global__ __launch_bounds__(256) void gemm_bt(
    const u16* __restrict__ A, const u16* __restrict__ Bt, int M, int N, int K,
    int nshift, const float* __restrict__ bias, u16* __restrict__ Cn,
    float* __restrict__ Cf, u16* __restrict__ Ct, long ct_stride,
    u16* __restrict__ Cn2, u16* __restrict__ Cn3,
    const float* __restrict__ gqq, const float* __restrict__ bqq,
    const float* __restrict__ gqk, const float* __restrict__ bqk,
    const float* __restrict__ glq, const float* __restrict__ blq,
    const float* __restrict__ glk, const float* __restrict__ blk) {
  __shared__ union {
    struct { u16 a[128 * 64]; u16 b[128 * 64]; } st;
    u16 tr[4 * 64 * 72];
  } sm;
  const int t = threadIdx.x;
  const int wave = t >> 6, lane = t & 63;
  const int l15 = lane & 15, l16 = lane >> 4;
  // XCD-aware tile decode (1-D grid)
  const int ell = blockIdx.x;
  const int xcd = ell & 7, i = ell >> 3;
  const int mtiles_per_xcd = M >> 10;  // (M/128)/8
  const int m0 = (xcd * mtiles_per_xcd + (i >> nshift)) * 128;
  const int n0 = (i & ((1 << nshift) - 1)) * 128;
  const int wm = (wave >> 1) * 64, wn = (wave & 1) * 64;

  floatx4 acc[4][4];
#pragma unroll
  for (int i2 = 0; i2 < 4; ++i2)
#pragma unroll
    for (int j = 0; j < 4; ++j) acc[i2][j] = fzero();

  // staging: 1024 chunks (16 B) each for A and B; 4 per thread per matrix
  const u16* pa[4];
  const u16* pb[4];
#pragma unroll
  for (int j = 0; j < 4; ++j) {
    const int c = t + 256 * j;
    const int r = c >> 3, p = c & 7;
    const int g = p ^ (r & 7);
    pa[j] = A + (size_t)(m0 + r) * K + g * 8;
    pb[j] = Bt + (size_t)(n0 + r) * K + g * 8;
  }

  for (int k0 = 0; k0 < K; k0 += 64) {
    __syncthreads();
#pragma unroll
    for (int j = 0; j < 4; ++j) {
      gll16(pa[j] + k0, &sm.st.a[(t + 256 * j) * 8]);
      gll16(pb[j] + k0, &sm.st.b[(t + 256 * j) * 8]);
    }
    __syncthreads();
#pragma unroll
    for (int s = 0; s < 2; ++s) {
      short8 af[4], bfr[4];
#pragma unroll
      for (int mi = 0; mi < 4; ++mi) {
        const int wr = wm + mi * 16 + l15;
        af[mi] = *(const short8*)&sm.st.a[wr * 64 + ((s * 4 + l16) ^ (wr & 7)) * 8];
      }
#pragma unroll
      for (int ni = 0; ni < 4; ++ni) {
        const int wr = wn + ni * 16 + l15;
        bfr[ni] = *(const short8*)&sm.st.b[wr * 64 + ((s * 4 + l16) ^ (wr & 7)) * 8];
      }
#pragma unroll
      for (int mi = 0; mi < 4; ++mi)
#pragma unroll
        for (int ni = 0; ni < 4; ++ni)
          acc[mi][ni] = mfma16(af[mi], bfr[ni], acc[mi][ni]);
    }
  }
  __syncthreads();

  if constexpr (MODE == 0) {
    u16* trw = &sm.tr[wave * 64 * 72];
#pragma unroll
    for (int mi = 0; mi < 4; ++mi)
#pragma unroll
      for (int ni = 0; ni < 4; ++ni) {
        const int col = n0 + wn + ni * 16 + l15;
        const float bc = bias[col];
#pragma unroll
        for (int r = 0; r < 4; ++r)
          trw[(mi * 16 + l16 * 4 + r) * 72 + ni * 16 + l15] =
              f2bf(silu_f(acc[mi][ni][r] + bc));
      }
#pragma unroll
    for (int it = 0; it < 8; ++it) {
      const int m_l = it * 8 + (lane >> 3);
      const int n_off = (lane & 7) * 8;
      *(short8*)&Cn[(size_t)(m0 + wm + m_l) * N + n0 + wn + n_off] =
          *(const short8*)&trw[m_l * 72 + n_off];
    }
  } else if constexpr (MODE == 3) {
#pragma unroll
    for (int mi = 0; mi < 4; ++mi)
#pragma unroll
      for (int ni = 0; ni < 4; ++ni) {
        const int col = n0 + wn + ni * 16 + l15;
        const float bc = bias[col];
        const int row = m0 + wm + mi * 16 + l16 * 4;
#pragma unroll
        for (int r = 0; r < 4; ++r)
          Cf[(size_t)(row + r) * N + col] = acc[mi][ni][r] + bc;
      }
  } else if constexpr (MODE == 1) {
    u16* trw = &sm.tr[wave * 64 * 72];
#pragma unroll
    for (int mi = 0; mi < 4; ++mi)
#pragma unroll
      for (int ni = 0; ni < 4; ++ni) {
        const int col = n0 + wn + ni * 16 + l15;
        const float bc = bias[col];
        ushort4v p;
#pragma unroll
        for (int r = 0; r < 4; ++r) p[r] = f2bf(silu_f(acc[mi][ni][r] + bc));
        *(ushort4v*)&trw[(ni * 16 + l15) * 72 + mi * 16 + l16 * 4] = p;
      }
    wave_transposed_store(Ct, ct_stride, trw, (m0 + wm) >> 8, (m0 + wm) & 255,
                          n0 + wn, lane);
  } else {  // MODE 2
    u16* trw = &sm.tr[wave * 64 * 72];
#pragma unroll
    for (int mi = 0; mi < 4; ++mi)
#pragma unroll
      for (int ni = 0; ni < 4; ++ni) {
        const int col = wn + ni * 16 + l15;
        const float bc = bias[col];
        const float Gqq = gqq[col], Bqq = bqq[col];
        const float Gqk = gqk[col], Bqk = bqk[col];
        const float Glq = glq[col], Blq = blq[col];
        const float Glk = glk[col], Blk = blk[col];
        const int row = m0 + wm + mi * 16 + l16 * 4;
        ushort4v p;
#pragma unroll
        for (int r = 0; r < 4; ++r) {
          const float sv = silu_f(acc[mi][ni][r] + bc);
          const size_t ad = (size_t)(row + r) * N + col;
          Cn[ad] = f2bf(sv * Gqq + Bqq);
          Cn2[ad] = f2bf(sv * Gqk + Bqk);
          Cn3[ad] = f2bf(sv * Glq + Blq);
          p[r] = f2bf(sv * Glk + Blk);
        }
        *(ushort4v*)&trw[(ni * 16 + l15) * 72 + mi * 16 + l16 * 4] = p;
      }
    wave_transposed_store(Ct, ct_stride, trw, (m0 + wm) >> 8, (m0 + wm) & 255, wn,
                          lane);
  }
}

// ---------------- per-chunk kv[e][h] = sum_c vT[e][c]*lkT[h][c] ----------------
__global__ __launch_bounds__(256) void kv_kernel(const u16* __restrict__ vT,
                                                 const u16* __restrict__ lkT,
                                                 u16* __restrict__ kv) {
  const int chunk = blockIdx.y;
  const int et = blockIdx.x;  // e-block of 128
  const int w = threadIdx.x >> 6, lane = threadIdx.x & 63;
  const int l15 = lane & 15, l16 = lane >> 4;
  const size_t vb = (size_t)chunk * (2048 * 256) + (size_t)et * (128 * 256);
  const size_t lb = (size_t)chunk * (128 * 256);
  const int we = (w >> 1) * 64, wh = (w & 1) * 64;
  floatx4 acc[4][4];
#pragma unroll
  for (int i = 0; i < 4; ++i)
#pragma unroll
    for (int j = 0; j < 4; ++j) acc[i][j] = fzero();
  for (int kk = 0; kk < 8; ++kk) {
    short8 av[4], bv[4];
#pragma unroll
    for (int mi = 0; mi < 4; ++mi)
      av[mi] = *(const short8*)&vT[vb + (size_t)(we + mi * 16 + l15) * 256 + kk * 32 +
                                   l16 * 8];
#pragma unroll
    for (int ni = 0; ni < 4; ++ni)
      bv[ni] = *(const short8*)&lkT[lb + (size_t)(wh + ni * 16 + l15) * 256 + kk * 32 +
                                    l16 * 8];
#pragma unroll
    for (int mi = 0; mi < 4; ++mi)
#pragma unroll
      for (int ni = 0; ni < 4; ++ni) acc[mi][ni] = mfma16(av[mi], bv[ni], acc[mi][ni]);
  }
  u16* out = kv + (size_t)chunk * (2048 * 128);
#pragma unroll
  for (int mi = 0; mi < 4; ++mi)
#pragma unroll
    for (int ni = 0; ni < 4; ++ni) {
      const int h = wh + ni * 16 + l15;
      const int e = et * 128 + we + mi * 16 + l16 * 4;
#pragma unroll
      for (int r = 0; r < 4; ++r) out[(size_t)(e + r) * 128 + h] = f2bf(acc[mi][ni][r]);
    }
}

// ---------------- exclusive cumsum over chunks (in place, bf16) ----------------
__global__ __launch_bounds__(256) void cumsum_kernel(u16* __restrict__ kv) {
  const int idx = blockIdx.x * 256 + threadIdx.x;  // 0..262143 (= 2048*128)
  const int b = blockIdx.y;
  float s = 0.f;
  for (int g = 0; g < 16; ++g) {
    const size_t a = (size_t)(b * 16 + g) * 262144 + idx;
    const float v = bf2f(kv[a]);
    kv[a] = f2bf(s);
    s += v;
  }
}

// ---------------- fused chunk attention ----------------
__global__ __launch_bounds__(256) void attn_kernel(
    const u16* __restrict__ qq, const u16* __restrict__ qk, const u16* __restrict__ lq,
    const u16* __restrict__ vT, const u16* __restrict__ kvT,
    u16* __restrict__ gate_op) {
  __shared__ u16 S[64][264];
  const int chunk = blockIdx.y;
  const int e0 = blockIdx.x * 256;
  const int tok0 = chunk * 256;
  const int w = threadIdx.x >> 6, lane = threadIdx.x & 63;
  const int l15 = lane & 15, l16 = lane >> 4;
  const float isc = 0.022097086912079608f;  // 1/sqrt(2048)
  const size_t vbase = (size_t)chunk * (2048 * 256);
  const size_t kbase = (size_t)chunk * (2048 * 128);
  const int ew = e0 + w * 64;

  for (int ns = 0; ns < 4; ++ns) {
    // ---- phase 1: S rows [ns*64+w*16, +16) = relu^2(mask(qq*qk^T/scale))
    const int r0 = ns * 64 + w * 16;
    short8 af[4];
#pragma unroll
    for (int kk = 0; kk < 4; ++kk)
      af[kk] = *(const short8*)&qq[(size_t)(tok0 + r0 + l15) * 128 + kk * 32 + l16 * 8];
    const int mt_cnt = (r0 >> 4) + 1;   // tiles with any unmasked entry
    const int mt_all = (ns + 1) * 4;    // tiles phase 2 will read
    const int srow = w * 16 + l16 * 4;
    for (int mt = 0; mt < mt_all; ++mt) {
      if (mt < mt_cnt) {
        floatx4 a = fzero();
#pragma unroll
        for (int kk = 0; kk < 4; ++kk) {
          short8 bq =
              *(const short8*)&qk[(size_t)(tok0 + mt * 16 + l15) * 128 + kk * 32 +
                                  l16 * 8];
          a = mfma16(af[kk], bq, a);
        }
        const int mcol = mt * 16 + l15;
#pragma unroll
        for (int r = 0; r < 4; ++r) {
          const int nrow = r0 + l16 * 4 + r;
          float sv = a[r] * isc;
          sv = (mcol <= nrow) ? sv : 0.f;
          sv = fmaxf(sv, 0.f);
          S[srow + r][mcol] = f2bf(sv * sv);
        }
      } else {
#pragma unroll
        for (int r = 0; r < 4; ++r) S[srow + r][mt * 16 + l15] = (u16)0;
      }
    }
    __syncthreads();

    // ---- phase 2: (S@v + lin_q@kv) * gate, wave covers e cols [ew, ew+64)
    floatx4 acc[4][4];
#pragma unroll
    for (int i = 0; i < 4; ++i)
#pragma unroll
      for (int j = 0; j < 4; ++j) acc[i][j] = fzero();

    const int ks = (ns + 1) * 2;  // causal truncation of K range
    for (int kk = 0; kk < ks; ++kk) {
      short8 sa[4];
#pragma unroll
      for (int nt = 0; nt < 4; ++nt)
        sa[nt] = *(const short8*)&S[nt * 16 + l15][kk * 32 + l16 * 8];
#pragma unroll
      for (int ei = 0; ei < 4; ++ei) {
        short8 vb = *(const short8*)&vT[vbase + (size_t)(ew + ei * 16 + l15) * 256 +
                                        kk * 32 + l16 * 8];
#pragma unroll
        for (int nt = 0; nt < 4; ++nt) acc[nt][ei] = mfma16(sa[nt], vb, acc[nt][ei]);
      }
    }
#pragma unroll
    for (int kk = 0; kk < 4; ++kk) {
      short8 la[4];
#pragma unroll
      for (int nt = 0; nt < 4; ++nt)
        la[nt] = *(const short8*)&lq[(size_t)(tok0 + ns * 64 + nt * 16 + l15) * 128 +
                                     kk * 32 + l16 * 8];
#pragma unroll
      for (int ei = 0; ei < 4; ++ei) {
        short8 kb = *(const short8*)&kvT[kbase + (size_t)(ew + ei * 16 + l15) * 128 +
                                         kk * 32 + l16 * 8];
#pragma unroll
        for (int nt = 0; nt < 4; ++nt) acc[nt][ei] = mfma16(la[nt], kb, acc[nt][ei]);
      }
    }
#pragma unroll
    for (int nt = 0; nt < 4; ++nt)
#pragma unroll
      for (int ei = 0; ei < 4; ++ei) {
        const int e_g = ew + ei * 16 + l15;
        const int nb = tok0 + ns * 64 + nt * 16 + l16 * 4;
#pragma unroll
        for (int r = 0; r < 4; ++r) {
          const size_t ad = (size_t)(nb + r) * 2048 + e_g;
          const float gv = bf2f(gate_op[ad]);
          gate_op[ad] = f2bf(acc[nt][ei][r] * gv);
        }
      }
    __syncthreads();
  }
}

extern "C" void kernel_launch(void* const* d_in, const int* in_sizes, int n_in,
                              void* d_out, int out_size, void* d_ws, size_t ws_size,
                              hipStream_t stream) {
  (void)in_sizes; (void)n_in; (void)out_size; (void)ws_size;
  const float* x = (const float*)d_in[0];
  const float* Wv = (const float*)d_in[1];
  const float* bv = (const float*)d_in[2];
  const float* Wg = (const float*)d_in[3];
  const float* bg = (const float*)d_in[4];
  const float* Win = (const float*)d_in[5];
  const float* bin = (const float*)d_in[6];
  const float* Wout = (const float*)d_in[7];
  const float* bout = (const float*)d_in[8];
  const float* gqq = (const float*)d_in[9];
  const float* bqq = (const float*)d_in[10];
  const float* gqk = (const float*)d_in[11];
  const float* bqk = (const float*)d_in[12];
  const float* glq = (const float*)d_in[13];
  const float* blq = (const float*)d_in[14];
  const float* glk = (const float*)d_in[15];
  const float* blk = (const float*)d_in[16];

  char* p = (char*)d_ws;
  u16* xb = (u16*)p;   p += (size_t)16384 * 1024 * 2;
  u16* wvT = (u16*)p;  p += (size_t)2048 * 1024 * 2;
  u16* wgT = (u16*)p;  p += (size_t)2048 * 1024 * 2;
  u16* winT = (u16*)p; p += (size_t)128 * 1024 * 2;
  u16* woT = (u16*)p;  p += (size_t)1024 * 2048 * 2;
  u16* vTb = (u16*)p;  p += (size_t)64 * 2048 * 256 * 2;
  u16* gate = (u16*)p; p += (size_t)16384 * 2048 * 2;  // gate, then op (in place)
  u16* qqb = (u16*)p;  p += (size_t)16384 * 128 * 2;
  u16* qkb = (u16*)p;  p += (size_t)16384 * 128 * 2;
  u16* lqb = (u16*)p;  p += (size_t)16384 * 128 * 2;
  u16* lkTb = (u16*)p; p += (size_t)64 * 128 * 256 * 2;
  u16* kvb = (u16*)p;  p += (size_t)64 * 2048 * 128 * 2;

  cast_x_kernel<<<16384, 256, 0, stream>>>(x, xb, 4194304);
  transpose_cast_kernel<<<dim3(64, 32), 256, 0, stream>>>(Wv, wvT, 1024, 2048);
  transpose_cast_kernel<<<dim3(64, 32), 256, 0, stream>>>(Wg, wgT, 1024, 2048);
  transpose_cast_kernel<<<dim3(4, 32), 256, 0, stream>>>(Win, winT, 1024, 128);
  transpose_cast_kernel<<<dim3(32, 64), 256, 0, stream>>>(Wout, woT, 2048, 1024);

  gemm_bt<1><<<2048, 256, 0, stream>>>(
      xb, wvT, 16384, 2048, 1024, 4, bv, nullptr, nullptr, vTb, 2048L * 256, nullptr,
      nullptr, nullptr, nullptr, nullptr, nullptr, nullptr, nullptr, nullptr, nullptr);
  gemm_bt<0><<<2048, 256, 0, stream>>>(
      xb, wgT, 16384, 2048, 1024, 4, bg, gate, nullptr, nullptr, 0, nullptr, nullptr,
      nullptr, nullptr, nullptr, nullptr, nullptr, nullptr, nullptr, nullptr);
  gemm_bt<2><<<128, 256, 0, stream>>>(
      xb, winT, 16384, 128, 1024, 0, bin, qqb, nullptr, lkTb, 128L * 256, qkb, lqb,
      gqq, bqq, gqk, bqk, glq, blq, glk, blk);

  kv_kernel<<<dim3(16, 64), 256, 0, stream>>>(vTb, lkTb, kvb);
  cumsum_kernel<<<dim3(1024, 4), 256, 0, stream>>>(kvb);
  attn_kernel<<<dim3(8, 64), 256, 0, stream>>>(qqb, qkb, lqb, vTb, kvb, gate);

  gemm_bt<3><<<1024, 256, 0, stream>>>(
      gate, woT, 16384, 1024, 2048, 3, bout, nullptr, (float*)d_out, nullptr, 0,
      nullptr, nullptr, nullptr, nullptr, nullptr, nullptr, nullptr, nullptr, nullptr,
      nullptr);
}

// Round 4
// 559.651 us; speedup vs baseline: 1.2005x; 1.0750x over previous
//
#include <hip/hip_runtime.h>

typedef __attribute__((ext_vector_type(8))) short short8;
typedef __attribute__((ext_vector_type(4))) float floatx4;
typedef __attribute__((ext_vector_type(4))) unsigned short ushort4v;
typedef unsigned short u16;

#define DEV __device__ __forceinline__

DEV u16 f2bf(float f) {
  unsigned int u = __float_as_uint(f);
  u += 0x7fffu + ((u >> 16) & 1u);
  return (u16)(u >> 16);
}
DEV float bf2f(u16 h) { return __uint_as_float(((unsigned int)h) << 16); }
DEV float silu_f(float x) { return x / (1.f + __expf(-x)); }
DEV floatx4 fzero() { floatx4 z = {0.f, 0.f, 0.f, 0.f}; return z; }
DEV floatx4 mfma16(short8 a, short8 b, floatx4 c) {
  return __builtin_amdgcn_mfma_f32_16x16x32_bf16(a, b, c, 0, 0, 0);
}
DEV void gll16(const void* g, void* l) {
  __builtin_amdgcn_global_load_lds((__attribute__((address_space(1))) void*)g,
                                   (__attribute__((address_space(3))) void*)l,
                                   16, 0, 0);
}

// ---------------- cast x (f32 -> bf16) ----------------
__global__ __launch_bounds__(256) void cast_x_kernel(const float* __restrict__ x,
                                                     u16* __restrict__ xb, int n4) {
  int i = blockIdx.x * 256 + threadIdx.x;
  if (i >= n4) return;
  float4 v = ((const float4*)x)[i];
  ushort4v o;
  o[0] = f2bf(v.x); o[1] = f2bf(v.y); o[2] = f2bf(v.z); o[3] = f2bf(v.w);
  *(ushort4v*)&xb[(size_t)i * 4] = o;
}

// ---------------- transpose+cast: W[K][N] f32 -> WT[N][K] bf16 ----------------
__global__ __launch_bounds__(256) void transpose_cast_kernel(const float* __restrict__ W,
                                                             u16* __restrict__ WT,
                                                             int K, int N) {
  __shared__ u16 tile[32][36];
  int n0 = blockIdx.x * 32, k0 = blockIdx.y * 32;
  int t = threadIdx.x;
  int r = t >> 3, cs = (t & 7) * 4;
  float4 v = *(const float4*)&W[(size_t)(k0 + r) * N + n0 + cs];
  tile[r][cs + 0] = f2bf(v.x);
  tile[r][cs + 1] = f2bf(v.y);
  tile[r][cs + 2] = f2bf(v.z);
  tile[r][cs + 3] = f2bf(v.w);
  __syncthreads();
  ushort4v o;
  o[0] = tile[cs + 0][r];
  o[1] = tile[cs + 1][r];
  o[2] = tile[cs + 2][r];
  o[3] = tile[cs + 3][r];
  *(ushort4v*)&WT[(size_t)(n0 + r) * K + k0 + cs] = o;
}

// ---------------- transposed bf16 store helper (wave 64x64 tile in tr[64][72]) ----
DEV void wave_transposed_store(u16* __restrict__ Ct, long chunk_stride,
                               const u16* trw, int chunk, int cbase, int nbase,
                               int lane) {
#pragma unroll
  for (int it = 0; it < 8; ++it) {
    int e_l = it * 8 + (lane >> 3);
    int c_off = (lane & 7) * 8;
    short8 val = *(const short8*)&trw[e_l * 72 + c_off];
    *(short8*)&Ct[(size_t)chunk * chunk_stride + (size_t)(nbase + e_l) * 256 + cbase +
                  c_off] = val;
  }
}

// =============== fused v+gate GEMM: one A-stage feeds two B matrices ===========
// M=16384 N=2048 K=1024. 128x128 tile per block for BOTH outputs.
// LDS rows 128 B, chunk p of row r holds global chunk p^(r&7) (conflict-free).
// XCD-aware 1-D grid decode as in gemm_bt.
__global__ __launch_bounds__(256, 2) void gemm_vg(
    const u16* __restrict__ A, const u16* __restrict__ Bv, const u16* __restrict__ Bg,
    const float* __restrict__ bvb, const float* __restrict__ bgb,
    u16* __restrict__ vT, u16* __restrict__ gate) {
  constexpr int K = 1024, N = 2048;
  __shared__ union {
    struct { u16 a[128 * 64]; u16 b[2][128 * 64]; } st;
    u16 tr[4 * 64 * 72];
  } sm;
  const int t = threadIdx.x;
  const int wave = t >> 6, lane = t & 63;
  const int l15 = lane & 15, l16 = lane >> 4;
  const int ell = blockIdx.x;
  const int xcd = ell & 7, i = ell >> 3;
  const int m0 = (xcd * 16 + (i >> 4)) * 128;
  const int n0 = (i & 15) * 128;
  const int wm = (wave >> 1) * 64, wn = (wave & 1) * 64;

  floatx4 accv[4][4], accg[4][4];
#pragma unroll
  for (int a = 0; a < 4; ++a)
#pragma unroll
    for (int b = 0; b < 4; ++b) { accv[a][b] = fzero(); accg[a][b] = fzero(); }

  const u16 *pa[4], *pbv[4], *pbg[4];
#pragma unroll
  for (int j = 0; j < 4; ++j) {
    const int c = t + 256 * j;
    const int r = c >> 3, p = c & 7;
    const int g = p ^ (r & 7);
    const size_t off = (size_t)r * K + g * 8;
    pa[j] = A + (size_t)m0 * K + off;
    pbv[j] = Bv + (size_t)n0 * K + off;
    pbg[j] = Bg + (size_t)n0 * K + off;
  }

  for (int k0 = 0; k0 < K; k0 += 64) {
    __syncthreads();
#pragma unroll
    for (int j = 0; j < 4; ++j) {
      const int d = (t + 256 * j) * 8;
      gll16(pa[j] + k0, &sm.st.a[d]);
      gll16(pbv[j] + k0, &sm.st.b[0][d]);
      gll16(pbg[j] + k0, &sm.st.b[1][d]);
    }
    __syncthreads();
#pragma unroll
    for (int s = 0; s < 2; ++s) {
      short8 af[4], b0[4], b1[4];
#pragma unroll
      for (int mi = 0; mi < 4; ++mi) {
        const int wr = wm + mi * 16 + l15;
        af[mi] = *(const short8*)&sm.st.a[wr * 64 + ((s * 4 + l16) ^ (wr & 7)) * 8];
      }
#pragma unroll
      for (int ni = 0; ni < 4; ++ni) {
        const int wr = wn + ni * 16 + l15;
        const int sl = wr * 64 + ((s * 4 + l16) ^ (wr & 7)) * 8;
        b0[ni] = *(const short8*)&sm.st.b[0][sl];
        b1[ni] = *(const short8*)&sm.st.b[1][sl];
      }
#pragma unroll
      for (int mi = 0; mi < 4; ++mi)
#pragma unroll
        for (int ni = 0; ni < 4; ++ni) {
          accv[mi][ni] = mfma16(af[mi], b0[ni], accv[mi][ni]);
          accg[mi][ni] = mfma16(af[mi], b1[ni], accg[mi][ni]);
        }
    }
  }
  __syncthreads();

  u16* trw = &sm.tr[wave * 64 * 72];
  // ---- epilogue 1: v -> silu -> transposed per-chunk store (vT)
#pragma unroll
  for (int mi = 0; mi < 4; ++mi)
#pragma unroll
    for (int ni = 0; ni < 4; ++ni) {
      const float bc = bvb[n0 + wn + ni * 16 + l15];
      ushort4v p;
#pragma unroll
      for (int r = 0; r < 4; ++r) p[r] = f2bf(silu_f(accv[mi][ni][r] + bc));
      *(ushort4v*)&trw[(ni * 16 + l15) * 72 + mi * 16 + l16 * 4] = p;
    }
  wave_transposed_store(vT, 2048L * 256, trw, (m0 + wm) >> 8, (m0 + wm) & 255,
                        n0 + wn, lane);
  // ---- epilogue 2: gate -> silu -> natural coalesced store via LDS transpose
#pragma unroll
  for (int mi = 0; mi < 4; ++mi)
#pragma unroll
    for (int ni = 0; ni < 4; ++ni) {
      const float bc = bgb[n0 + wn + ni * 16 + l15];
#pragma unroll
      for (int r = 0; r < 4; ++r)
        trw[(mi * 16 + l16 * 4 + r) * 72 + ni * 16 + l15] =
            f2bf(silu_f(accg[mi][ni][r] + bc));
    }
#pragma unroll
  for (int it = 0; it < 8; ++it) {
    const int m_l = it * 8 + (lane >> 3);
    const int n_off = (lane & 7) * 8;
    *(short8*)&gate[(size_t)(m0 + wm + m_l) * N + n0 + wn + n_off] =
        *(const short8*)&trw[m_l * 72 + n_off];
  }
}

// ---------------- GEMM: C = A[M,K] * Bt[N,K]^T, bf16 MFMA, 128x128, BK=64 ------
// MODE 2: silu -> qq/qk/lq natural (affine) + lkT transposed (affine)
// MODE 3: +bias -> fp32 natural (final output)
template <int MODE>
__global__ __launch_bounds__(256) void gemm_bt(
    const u16* __restrict__ A, const u16* __restrict__ Bt, int M, int N, int K,
    int nshift, const float* __restrict__ bias, u16* __restrict__ Cn,
    float* __restrict__ Cf, u16* __restrict__ Ct, long ct_stride,
    u16* __restrict__ Cn2, u16* __restrict__ Cn3,
    const float* __restrict__ gqq, const float* __restrict__ bqq,
    const float* __restrict__ gqk, const float* __restrict__ bqk,
    const float* __restrict__ glq, const float* __restrict__ blq,
    const float* __restrict__ glk, const float* __restrict__ blk) {
  __shared__ union {
    struct { u16 a[128 * 64]; u16 b[128 * 64]; } st;
    u16 tr[4 * 64 * 72];
  } sm;
  const int t = threadIdx.x;
  const int wave = t >> 6, lane = t & 63;
  const int l15 = lane & 15, l16 = lane >> 4;
  const int ell = blockIdx.x;
  const int xcd = ell & 7, i = ell >> 3;
  const int mtiles_per_xcd = M >> 10;
  const int m0 = (xcd * mtiles_per_xcd + (i >> nshift)) * 128;
  const int n0 = (i & ((1 << nshift) - 1)) * 128;
  const int wm = (wave >> 1) * 64, wn = (wave & 1) * 64;

  floatx4 acc[4][4];
#pragma unroll
  for (int i2 = 0; i2 < 4; ++i2)
#pragma unroll
    for (int j = 0; j < 4; ++j) acc[i2][j] = fzero();

  const u16* pa[4];
  const u16* pb[4];
#pragma unroll
  for (int j = 0; j < 4; ++j) {
    const int c = t + 256 * j;
    const int r = c >> 3, p = c & 7;
    const int g = p ^ (r & 7);
    pa[j] = A + (size_t)(m0 + r) * K + g * 8;
    pb[j] = Bt + (size_t)(n0 + r) * K + g * 8;
  }

  for (int k0 = 0; k0 < K; k0 += 64) {
    __syncthreads();
#pragma unroll
    for (int j = 0; j < 4; ++j) {
      gll16(pa[j] + k0, &sm.st.a[(t + 256 * j) * 8]);
      gll16(pb[j] + k0, &sm.st.b[(t + 256 * j) * 8]);
    }
    __syncthreads();
#pragma unroll
    for (int s = 0; s < 2; ++s) {
      short8 af[4], bfr[4];
#pragma unroll
      for (int mi = 0; mi < 4; ++mi) {
        const int wr = wm + mi * 16 + l15;
        af[mi] = *(const short8*)&sm.st.a[wr * 64 + ((s * 4 + l16) ^ (wr & 7)) * 8];
      }
#pragma unroll
      for (int ni = 0; ni < 4; ++ni) {
        const int wr = wn + ni * 16 + l15;
        bfr[ni] = *(const short8*)&sm.st.b[wr * 64 + ((s * 4 + l16) ^ (wr & 7)) * 8];
      }
#pragma unroll
      for (int mi = 0; mi < 4; ++mi)
#pragma unroll
        for (int ni = 0; ni < 4; ++ni)
          acc[mi][ni] = mfma16(af[mi], bfr[ni], acc[mi][ni]);
    }
  }
  __syncthreads();

  if constexpr (MODE == 3) {
#pragma unroll
    for (int mi = 0; mi < 4; ++mi)
#pragma unroll
      for (int ni = 0; ni < 4; ++ni) {
        const int col = n0 + wn + ni * 16 + l15;
        const float bc = bias[col];
        const int row = m0 + wm + mi * 16 + l16 * 4;
#pragma unroll
        for (int r = 0; r < 4; ++r)
          Cf[(size_t)(row + r) * N + col] = acc[mi][ni][r] + bc;
      }
  } else {  // MODE 2
    u16* trw = &sm.tr[wave * 64 * 72];
#pragma unroll
    for (int mi = 0; mi < 4; ++mi)
#pragma unroll
      for (int ni = 0; ni < 4; ++ni) {
        const int col = wn + ni * 16 + l15;
        const float bc = bias[col];
        const float Gqq = gqq[col], Bqq = bqq[col];
        const float Gqk = gqk[col], Bqk = bqk[col];
        const float Glq = glq[col], Blq = blq[col];
        const float Glk = glk[col], Blk = blk[col];
        const int row = m0 + wm + mi * 16 + l16 * 4;
        ushort4v p;
#pragma unroll
        for (int r = 0; r < 4; ++r) {
          const float sv = silu_f(acc[mi][ni][r] + bc);
          const size_t ad = (size_t)(row + r) * N + col;
          Cn[ad] = f2bf(sv * Gqq + Bqq);
          Cn2[ad] = f2bf(sv * Gqk + Bqk);
          Cn3[ad] = f2bf(sv * Glq + Blq);
          p[r] = f2bf(sv * Glk + Blk);
        }
        *(ushort4v*)&trw[(ni * 16 + l15) * 72 + mi * 16 + l16 * 4] = p;
      }
    wave_transposed_store(Ct, ct_stride, trw, (m0 + wm) >> 8, (m0 + wm) & 255, wn,
                          lane);
  }
}

// ---------------- per-chunk kv[e][h] = sum_c vT[e][c]*lkT[h][c] ----------------
__global__ __launch_bounds__(256) void kv_kernel(const u16* __restrict__ vT,
                                                 const u16* __restrict__ lkT,
                                                 u16* __restrict__ kv) {
  const int chunk = blockIdx.y;
  const int et = blockIdx.x;  // e-block of 128
  const int w = threadIdx.x >> 6, lane = threadIdx.x & 63;
  const int l15 = lane & 15, l16 = lane >> 4;
  const size_t vb = (size_t)chunk * (2048 * 256) + (size_t)et * (128 * 256);
  const size_t lb = (size_t)chunk * (128 * 256);
  const int we = (w >> 1) * 64, wh = (w & 1) * 64;
  floatx4 acc[4][4];
#pragma unroll
  for (int i = 0; i < 4; ++i)
#pragma unroll
    for (int j = 0; j < 4; ++j) acc[i][j] = fzero();
  for (int kk = 0; kk < 8; ++kk) {
    short8 av[4], bv[4];
#pragma unroll
    for (int mi = 0; mi < 4; ++mi)
      av[mi] = *(const short8*)&vT[vb + (size_t)(we + mi * 16 + l15) * 256 + kk * 32 +
                                   l16 * 8];
#pragma unroll
    for (int ni = 0; ni < 4; ++ni)
      bv[ni] = *(const short8*)&lkT[lb + (size_t)(wh + ni * 16 + l15) * 256 + kk * 32 +
                                    l16 * 8];
#pragma unroll
    for (int mi = 0; mi < 4; ++mi)
#pragma unroll
      for (int ni = 0; ni < 4; ++ni) acc[mi][ni] = mfma16(av[mi], bv[ni], acc[mi][ni]);
  }
  u16* out = kv + (size_t)chunk * (2048 * 128);
#pragma unroll
  for (int mi = 0; mi < 4; ++mi)
#pragma unroll
    for (int ni = 0; ni < 4; ++ni) {
      const int h = wh + ni * 16 + l15;
      const int e = et * 128 + we + mi * 16 + l16 * 4;
#pragma unroll
      for (int r = 0; r < 4; ++r) out[(size_t)(e + r) * 128 + h] = f2bf(acc[mi][ni][r]);
    }
}

// ---------------- exclusive cumsum over chunks (in place, bf16) ----------------
__global__ __launch_bounds__(256) void cumsum_kernel(u16* __restrict__ kv) {
  const int idx = blockIdx.x * 256 + threadIdx.x;  // 0..262143 (= 2048*128)
  const int b = blockIdx.y;
  float s = 0.f;
  for (int g = 0; g < 16; ++g) {
    const size_t a = (size_t)(b * 16 + g) * 262144 + idx;
    const float v = bf2f(kv[a]);
    kv[a] = f2bf(s);
    s += v;
  }
}

// ---------------- fused chunk attention ----------------
__global__ __launch_bounds__(256) void attn_kernel(
    const u16* __restrict__ qq, const u16* __restrict__ qk, const u16* __restrict__ lq,
    const u16* __restrict__ vT, const u16* __restrict__ kvT,
    u16* __restrict__ gate_op) {
  __shared__ u16 S[64][264];
  const int chunk = blockIdx.y;
  const int e0 = blockIdx.x * 256;
  const int tok0 = chunk * 256;
  const int w = threadIdx.x >> 6, lane = threadIdx.x & 63;
  const int l15 = lane & 15, l16 = lane >> 4;
  const float isc = 0.022097086912079608f;  // 1/sqrt(2048)
  const size_t vbase = (size_t)chunk * (2048 * 256);
  const size_t kbase = (size_t)chunk * (2048 * 128);
  const int ew = e0 + w * 64;

  for (int ns = 0; ns < 4; ++ns) {
    // ---- phase 1: S rows [ns*64+w*16, +16) = relu^2(mask(qq*qk^T/scale))
    const int r0 = ns * 64 + w * 16;
    short8 af[4];
#pragma unroll
    for (int kk = 0; kk < 4; ++kk)
      af[kk] = *(const short8*)&qq[(size_t)(tok0 + r0 + l15) * 128 + kk * 32 + l16 * 8];
    const int mt_cnt = (r0 >> 4) + 1;   // tiles with any unmasked entry
    const int mt_all = (ns + 1) * 4;    // tiles phase 2 will read
    const int srow = w * 16 + l16 * 4;
    for (int mt = 0; mt < mt_all; ++mt) {
      if (mt < mt_cnt) {
        floatx4 a = fzero();
#pragma unroll
        for (int kk = 0; kk < 4; ++kk) {
          short8 bq =
              *(const short8*)&qk[(size_t)(tok0 + mt * 16 + l15) * 128 + kk * 32 +
                                  l16 * 8];
          a = mfma16(af[kk], bq, a);
        }
        const int mcol = mt * 16 + l15;
#pragma unroll
        for (int r = 0; r < 4; ++r) {
          const int nrow = r0 + l16 * 4 + r;
          float sv = a[r] * isc;
          sv = (mcol <= nrow) ? sv : 0.f;
          sv = fmaxf(sv, 0.f);
          S[srow + r][mcol] = f2bf(sv * sv);
        }
      } else {
#pragma unroll
        for (int r = 0; r < 4; ++r) S[srow + r][mt * 16 + l15] = (u16)0;
      }
    }
    __syncthreads();

    // ---- phase 2: (S@v + lin_q@kv) * gate, wave covers e cols [ew, ew+64)
    floatx4 acc[4][4];
#pragma unroll
    for (int i = 0; i < 4; ++i)
#pragma unroll
      for (int j = 0; j < 4; ++j) acc[i][j] = fzero();

    const int ks = (ns + 1) * 2;  // causal truncation of K range
    for (int kk = 0; kk < ks; ++kk) {
      short8 sa[4];
#pragma unroll
      for (int nt = 0; nt < 4; ++nt)
        sa[nt] = *(const short8*)&S[nt * 16 + l15][kk * 32 + l16 * 8];
#pragma unroll
      for (int ei = 0; ei < 4; ++ei) {
        short8 vb = *(const short8*)&vT[vbase + (size_t)(ew + ei * 16 + l15) * 256 +
                                        kk * 32 + l16 * 8];
#pragma unroll
        for (int nt = 0; nt < 4; ++nt) acc[nt][ei] = mfma16(sa[nt], vb, acc[nt][ei]);
      }
    }
#pragma unroll
    for (int kk = 0; kk < 4; ++kk) {
      short8 la[4];
#pragma unroll
      for (int nt = 0; nt < 4; ++nt)
        la[nt] = *(const short8*)&lq[(size_t)(tok0 + ns * 64 + nt * 16 + l15) * 128 +
                                     kk * 32 + l16 * 8];
#pragma unroll
      for (int ei = 0; ei < 4; ++ei) {
        short8 kb = *(const short8*)&kvT[kbase + (size_t)(ew + ei * 16 + l15) * 128 +
                                         kk * 32 + l16 * 8];
#pragma unroll
        for (int nt = 0; nt < 4; ++nt) acc[nt][ei] = mfma16(la[nt], kb, acc[nt][ei]);
      }
    }
#pragma unroll
    for (int nt = 0; nt < 4; ++nt)
#pragma unroll
      for (int ei = 0; ei < 4; ++ei) {
        const int e_g = ew + ei * 16 + l15;
        const int nb = tok0 + ns * 64 + nt * 16 + l16 * 4;
#pragma unroll
        for (int r = 0; r < 4; ++r) {
          const size_t ad = (size_t)(nb + r) * 2048 + e_g;
          const float gv = bf2f(gate_op[ad]);
          gate_op[ad] = f2bf(acc[nt][ei][r] * gv);
        }
      }
    __syncthreads();
  }
}

extern "C" void kernel_launch(void* const* d_in, const int* in_sizes, int n_in,
                              void* d_out, int out_size, void* d_ws, size_t ws_size,
                              hipStream_t stream) {
  (void)in_sizes; (void)n_in; (void)out_size; (void)ws_size;
  const float* x = (const float*)d_in[0];
  const float* Wv = (const float*)d_in[1];
  const float* bv = (const float*)d_in[2];
  const float* Wg = (const float*)d_in[3];
  const float* bg = (const float*)d_in[4];
  const float* Win = (const float*)d_in[5];
  const float* bin = (const float*)d_in[6];
  const float* Wout = (const float*)d_in[7];
  const float* bout = (const float*)d_in[8];
  const float* gqq = (const float*)d_in[9];
  const float* bqq = (const float*)d_in[10];
  const float* gqk = (const float*)d_in[11];
  const float* bqk = (const float*)d_in[12];
  const float* glq = (const float*)d_in[13];
  const float* blq = (const float*)d_in[14];
  const float* glk = (const float*)d_in[15];
  const float* blk = (const float*)d_in[16];

  char* p = (char*)d_ws;
  u16* xb = (u16*)p;   p += (size_t)16384 * 1024 * 2;
  u16* wvT = (u16*)p;  p += (size_t)2048 * 1024 * 2;
  u16* wgT = (u16*)p;  p += (size_t)2048 * 1024 * 2;
  u16* winT = (u16*)p; p += (size_t)128 * 1024 * 2;
  u16* woT = (u16*)p;  p += (size_t)1024 * 2048 * 2;
  u16* vTb = (u16*)p;  p += (size_t)64 * 2048 * 256 * 2;
  u16* gate = (u16*)p; p += (size_t)16384 * 2048 * 2;  // gate, then op (in place)
  u16* qqb = (u16*)p;  p += (size_t)16384 * 128 * 2;
  u16* qkb = (u16*)p;  p += (size_t)16384 * 128 * 2;
  u16* lqb = (u16*)p;  p += (size_t)16384 * 128 * 2;
  u16* lkTb = (u16*)p; p += (size_t)64 * 128 * 256 * 2;
  u16* kvb = (u16*)p;  p += (size_t)64 * 2048 * 128 * 2;

  cast_x_kernel<<<16384, 256, 0, stream>>>(x, xb, 4194304);
  transpose_cast_kernel<<<dim3(64, 32), 256, 0, stream>>>(Wv, wvT, 1024, 2048);
  transpose_cast_kernel<<<dim3(64, 32), 256, 0, stream>>>(Wg, wgT, 1024, 2048);
  transpose_cast_kernel<<<dim3(4, 32), 256, 0, stream>>>(Win, winT, 1024, 128);
  transpose_cast_kernel<<<dim3(32, 64), 256, 0, stream>>>(Wout, woT, 2048, 1024);

  gemm_vg<<<2048, 256, 0, stream>>>(xb, wvT, wgT, bv, bg, vTb, gate);
  gemm_bt<2><<<128, 256, 0, stream>>>(
      xb, winT, 16384, 128, 1024, 0, bin, qqb, nullptr, lkTb, 128L * 256, qkb, lqb,
      gqq, bqq, gqk, bqk, glq, blq, glk, blk);

  kv_kernel<<<dim3(16, 64), 256, 0, stream>>>(vTb, lkTb, kvb);
  cumsum_kernel<<<dim3(1024, 4), 256, 0, stream>>>(kvb);
  attn_kernel<<<dim3(8, 64), 256, 0, stream>>>(qqb, qkb, lqb, vTb, kvb, gate);

  gemm_bt<3><<<1024, 256, 0, stream>>>(
      gate, woT, 16384, 1024, 2048, 3, bout, nullptr, (float*)d_out, nullptr, 0,
      nullptr, nullptr, nullptr, nullptr, nullptr, nullptr, nullptr, nullptr, nullptr,
      nullptr);
}